// Round 2
// baseline (238.795 us; speedup 1.0000x reference)
//
#include <hip/hip_runtime.h>
#include <hip/hip_bf16.h>

#define EPSV 1e-8f

// ---------------------------------------------------------------------------
// Kernel 1: Householder QR of W = [weight | pose_weight] + EPS  (512 x 26),
// replicating LAPACK sgeqrf sign conventions (beta = -sign(alpha)*norm),
// then Q = W * R^{-1}, stored transposed as qt[26][512] in workspace.
//
// Register-resident version: thread i holds row i of A (and a pristine copy
// of W) entirely in VGPRs. The j-loop is fully unrolled so every register
// index is compile-time static. Per step:
//   - fused reduction of (sigma, S_{j+1..25}) via 6-stage shfl butterfly
//     + one cross-wave LDS round  (2 barriers/step, parity double-buffered)
//   - thread j publishes its row (needed for d_c and alpha) via LDS
//   - rank-1 update applied in registers
// ---------------------------------------------------------------------------

__global__ __launch_bounds__(512) void qr_kernel(const float* __restrict__ pose_w,
                                                 const float* __restrict__ lip_w,
                                                 float* __restrict__ qt) {
    __shared__ float partial[2][8][26];   // per-wave butterfly results
    __shared__ float tot[2][26];          // cross-wave totals
    __shared__ float rowj[2][26];         // pivot row (thread j's a[j..25])
    __shared__ float Rlds[26][27];        // final R (padded stride)
    __shared__ float Rinv[26][26];

    const int i    = threadIdx.x;         // row
    const int lane = i & 63;
    const int wid  = i >> 6;

    // Load W row i (concat order: weight[20] then pose_weight[6]) + EPS.
    float w[26], a[26];
    const float* lp = lip_w + i * 20;
#pragma unroll
    for (int m = 0; m < 20; ++m) w[m] = lp[m] + EPSV;
    const float* pp = pose_w + i * 6;
#pragma unroll
    for (int m = 0; m < 6; ++m) w[20 + m] = pp[m] + EPSV;
#pragma unroll
    for (int m = 0; m < 26; ++m) a[m] = w[m];

#pragma unroll
    for (int j = 0; j < 26; ++j) {
        const int buf = j & 1;
        const int R = 26 - j;             // values to reduce: sigma + S_{j+1..25}

        // Pivot row publish (alpha = rowj[j], a_{j,c} = rowj[c]).
        if (i == j) {
#pragma unroll
            for (int c = 0; c < 26; ++c)
                if (c >= j) rowj[buf][c] = a[c];
        }

        // Per-thread partials: p[0] = x_i^2 (i>=j), p[c-j] = x_i * a_ic (i>j).
        float p[26];
        const float xi  = (i >= j) ? a[j] : 0.f;
        const float xst = (i >  j) ? a[j] : 0.f;
        p[0] = xi * xi;
#pragma unroll
        for (int c = 0; c < 26; ++c)
            if (c > j) p[c - j] = xst * a[c];

        // Intra-wave butterfly over all R values.
#pragma unroll
        for (int o = 32; o > 0; o >>= 1) {
#pragma unroll
            for (int v = 0; v < 26; ++v)
                if (v < R) p[v] += __shfl_xor(p[v], o);
        }
        if (lane == 0) {
#pragma unroll
            for (int v = 0; v < 26; ++v)
                if (v < R) partial[buf][wid][v] = p[v];
        }
        __syncthreads();

        // Cross-wave finalize: thread v (< R) sums the 8 wave partials.
        if (i < R) {
            float s = 0.f;
#pragma unroll
            for (int ww = 0; ww < 8; ++ww) s += partial[buf][ww][i];
            tot[buf][i] = s;
        }
        __syncthreads();

        // Scalars (replicated in every thread).
        const float sigma  = tot[buf][0];
        const float alpha  = rowj[buf][j];
        const float normx  = sqrtf(sigma);
        // LAPACK slarfg: beta = -sign(alpha) * norm
        const float beta   = (alpha >= 0.f) ? -normx : normx;
        const float tau    = (beta - alpha) / beta;
        const float rdenom = 1.f / (alpha - beta);        // |alpha-beta| >= norm

        // Rank-1 update: a_ic -= tau * v_i * d_c,  d_c = a_jc + S_c/denom.
        // v_j = 1; v_i = x_i/denom (i>j); ti = tau*v_i (0 for i<j).
        const float ti = (i == j) ? tau
                       : ((i > j) ? tau * a[j] * rdenom : 0.f);
#pragma unroll
        for (int c = 0; c < 26; ++c) {
            if (c > j) {
                const float dc = fmaf(tot[buf][c - j], rdenom, rowj[buf][c]);
                a[c] = fmaf(-ti, dc, a[c]);
            }
        }
        if (i == j) a[j] = beta;          // R diagonal
    }

    // R rows live in threads 0..25; stage to LDS for back-substitution.
    if (i < 26) {
#pragma unroll
        for (int c = 0; c < 26; ++c)
            if (c >= i) Rlds[i][c] = a[c];
    }
    __syncthreads();

    // R^{-1} by back-substitution; thread c solves column c (independent).
    if (i < 26) {
        const int cc = i;
        for (int k = cc; k >= 0; --k) {
            float s = (k == cc) ? 1.f : 0.f;
            for (int m = k + 1; m <= cc; ++m) s -= Rlds[k][m] * Rinv[m][cc];
            Rinv[k][cc] = s / Rlds[k][k];
        }
    }
    __syncthreads();

    // Q = W * Rinv (W kept in registers). Store transposed:
    // qt[k*512 + i] = Q[i][k]. Rinv upper-triangular => m <= k.
#pragma unroll
    for (int k = 0; k < 26; ++k) {
        float q = 0.f;
#pragma unroll
        for (int m = 0; m < 26; ++m)
            if (m <= k) q = fmaf(w[m], Rinv[m][k], q);
        qt[k * 512 + i] = q;
    }
}

// ---------------------------------------------------------------------------
// Kernel 2: out[B][512] = input[B][26] @ qt^T   (qt is [26][512])
// Block = 256 threads handles 32 rows x 512 cols. Q fragment (26 x float4)
// in registers; input tile staged in LDS (broadcast reads); float4 stores.
// ---------------------------------------------------------------------------

__global__ __launch_bounds__(256) void out_gemm(const float* __restrict__ in,
                                                const float* __restrict__ qt,
                                                float* __restrict__ out) {
    __shared__ float xs[832];             // 32 rows x 26, linear
    const int tid = threadIdx.x;
    const long base = (long)blockIdx.x * 32;

    // Cooperative float4 load of the 32x26 input tile (832 floats = 208 f4).
    const float4* ip4 = reinterpret_cast<const float4*>(in + base * 26);
    if (tid < 208) reinterpret_cast<float4*>(xs)[tid] = ip4[tid];

    const int cg = tid & 127;             // column group: cols 4*cg .. 4*cg+3
    const int rh = tid >> 7;              // row half: 0 or 1

    float4 qf[26];
#pragma unroll
    for (int k = 0; k < 26; ++k)
        qf[k] = *reinterpret_cast<const float4*>(qt + k * 512 + cg * 4);
    __syncthreads();

    float* op = out + (base + (long)rh * 16) * 512 + cg * 4;
#pragma unroll
    for (int r = 0; r < 16; ++r) {
        const float* xr = xs + (rh * 16 + r) * 26;
        float ax = 0.f, ay = 0.f, az = 0.f, aw = 0.f;
#pragma unroll
        for (int k = 0; k < 26; ++k) {
            const float x = xr[k];
            ax = fmaf(x, qf[k].x, ax);
            ay = fmaf(x, qf[k].y, ay);
            az = fmaf(x, qf[k].z, az);
            aw = fmaf(x, qf[k].w, aw);
        }
        *reinterpret_cast<float4*>(op + (long)r * 512) = make_float4(ax, ay, az, aw);
    }
}

// ---------------------------------------------------------------------------

extern "C" void kernel_launch(void* const* d_in, const int* in_sizes, int n_in,
                              void* d_out, int out_size, void* d_ws, size_t ws_size,
                              hipStream_t stream) {
    const float* input  = (const float*)d_in[0];   // (B, 26)
    const float* pose_w = (const float*)d_in[1];   // (512, 6)
    const float* lip_w  = (const float*)d_in[2];   // (512, 20)
    float* out = (float*)d_out;                    // (B, 512)
    float* qt  = (float*)d_ws;                     // Q^T as [26][512] f32

    const int B = in_sizes[0] / 26;

    qr_kernel<<<1, 512, 0, stream>>>(pose_w, lip_w, qt);
    out_gemm<<<(B + 31) / 32, 256, 0, stream>>>(input, qt, out);
}

// Round 3
// 123.522 us; speedup vs baseline: 1.9332x; 1.9332x over previous
//
#include <hip/hip_runtime.h>
#include <hip/hip_bf16.h>

#define EPSV 1e-8f

// ---------------------------------------------------------------------------
// Householder QR of W = [weight | pose_weight] + EPS  (512 x 26), replicating
// LAPACK sgeqrf sign conventions (beta = -sign(alpha)*norm), then
// Q = W * R^{-1}, stored transposed as qt[26][512] in workspace.
//
// Single-wave register-resident core: lanes 0..63, lane l owns rows
// l, l+64, ..., l+448 (8 rows x 26 cols = 208 VGPRs, all statically indexed
// via template<int J> step instantiation -> no scratch). Per step:
//   - partials for {sigma, S_c} accumulated over the 8 local rows (VALU)
//   - 6-stage __shfl_xor butterfly -> sums replicated in-register
//   - pivot row broadcast via static-lane __shfl (v_readlane)
//   - rank-1 update applied in registers
// No barriers, no LDS in the 26-step chain.
// ---------------------------------------------------------------------------

__device__ __forceinline__ void load_w_row(const float* __restrict__ lip_w,
                                           const float* __restrict__ pose_w,
                                           int row, float* w) {
    // lip row: 20 floats, 80B-aligned rows -> 5x float4. pose row: 6 floats,
    // 24B-aligned rows -> 3x float2.
    const float4* lp4 = reinterpret_cast<const float4*>(lip_w + row * 20);
    float4 t0 = lp4[0], t1 = lp4[1], t2 = lp4[2], t3 = lp4[3], t4 = lp4[4];
    const float2* pp2 = reinterpret_cast<const float2*>(pose_w + row * 6);
    float2 u0 = pp2[0], u1 = pp2[1], u2 = pp2[2];
    w[0]  = t0.x + EPSV; w[1]  = t0.y + EPSV; w[2]  = t0.z + EPSV; w[3]  = t0.w + EPSV;
    w[4]  = t1.x + EPSV; w[5]  = t1.y + EPSV; w[6]  = t1.z + EPSV; w[7]  = t1.w + EPSV;
    w[8]  = t2.x + EPSV; w[9]  = t2.y + EPSV; w[10] = t2.z + EPSV; w[11] = t2.w + EPSV;
    w[12] = t3.x + EPSV; w[13] = t3.y + EPSV; w[14] = t3.z + EPSV; w[15] = t3.w + EPSV;
    w[16] = t4.x + EPSV; w[17] = t4.y + EPSV; w[18] = t4.z + EPSV; w[19] = t4.w + EPSV;
    w[20] = u0.x + EPSV; w[21] = u0.y + EPSV;
    w[22] = u1.x + EPSV; w[23] = u1.y + EPSV;
    w[24] = u2.x + EPSV; w[25] = u2.y + EPSV;
}

template<int J>
__device__ __forceinline__ void qr_step(float (&a)[8][26], const int lane) {
    // Partials: p[J] = sigma (rows >= J), p[c] = S_c = sum_{i>J} x_i * a_ic.
    float p[26];
    const float x0s = (lane >= J) ? a[0][J] : 0.f;   // row `lane` in sigma
    const float x0d = (lane >  J) ? a[0][J] : 0.f;   // row `lane` in tail dots
    p[J] = x0s * x0s;
#pragma unroll
    for (int s = 1; s < 8; ++s) p[J] = fmaf(a[s][J], a[s][J], p[J]);
#pragma unroll
    for (int c = J + 1; c < 26; ++c) {
        float t = x0d * a[0][c];
#pragma unroll
        for (int s = 1; s < 8; ++s) t = fmaf(a[s][J], a[s][c], t);
        p[c] = t;
    }

    // 6-stage butterfly: full sums replicated in every lane.
#pragma unroll
    for (int o = 32; o > 0; o >>= 1) {
#pragma unroll
        for (int c = J; c < 26; ++c) p[c] += __shfl_xor(p[c], o);
    }

    // Scalars (J is a literal lane -> v_readlane broadcast).
    const float alpha  = __shfl(a[0][J], J);
    const float normx  = sqrtf(p[J]);
    const float beta   = (alpha >= 0.f) ? -normx : normx;   // LAPACK slarfg
    const float tau    = (beta - alpha) / beta;
    const float rdenom = 1.f / (alpha - beta);              // |alpha-beta| >= norm

    // Per-row tau*v_i  (v_pivot = 1; v_i = x_i/(alpha-beta); rows < J -> 0).
    float t[8];
    t[0] = (lane == J) ? tau : tau * rdenom * x0d;
#pragma unroll
    for (int s = 1; s < 8; ++s) t[s] = tau * rdenom * a[s][J];

    // Rank-1 update: a_ic -= (tau v_i) * d_c,  d_c = a_Jc + S_c/(alpha-beta).
#pragma unroll
    for (int c = J + 1; c < 26; ++c) {
        const float rowjc = __shfl(a[0][c], J);   // read BEFORE this c's update
        const float dc = fmaf(p[c], rdenom, rowjc);
#pragma unroll
        for (int s = 0; s < 8; ++s) a[s][c] = fmaf(-t[s], dc, a[s][c]);
    }
    if (lane == J) a[0][J] = beta;                // R diagonal
}

template<int J> struct Steps {
    static __device__ __forceinline__ void run(float (&a)[8][26], int lane) {
        qr_step<J>(a, lane);
        Steps<J + 1>::run(a, lane);
    }
};
template<> struct Steps<26> {
    static __device__ __forceinline__ void run(float (&)[8][26], int) {}
};

__global__ __launch_bounds__(256) void qr_kernel(const float* __restrict__ pose_w,
                                                 const float* __restrict__ lip_w,
                                                 float* __restrict__ qt) {
    __shared__ float Rlds[26][27];
    __shared__ float Rinv[26][27];
    const int tid = threadIdx.x;

    if (tid < 64) {
        float a[8][26];
#pragma unroll
        for (int s = 0; s < 8; ++s)
            load_w_row(lip_w, pose_w, tid + 64 * s, a[s]);

        Steps<0>::run(a, tid);

        // R row j lives in lane j, slot 0 (final after step j; later steps
        // leave rows < J untouched since their tau*v_i mask is 0).
        if (tid < 26) {
#pragma unroll
            for (int c = 0; c < 26; ++c)
                if (c >= tid) Rlds[tid][c] = a[0][c];
        }
    }
    __syncthreads();

    // R^{-1} by back-substitution; thread c solves column c (independent).
    if (tid < 26) {
        const int cc = tid;
        for (int k = cc; k >= 0; --k) {
            float s = (k == cc) ? 1.f : 0.f;
            for (int m = k + 1; m <= cc; ++m) s -= Rlds[k][m] * Rinv[m][cc];
            Rinv[k][cc] = s / Rlds[k][k];
        }
    }
    __syncthreads();

    // Q = W * Rinv, stored transposed: qt[k*512 + i] = Q[i][k].
    // 256 threads x 2 rows (i = tid, tid+256); Rinv upper-tri => m <= k.
    float w0[26], w1[26];
    load_w_row(lip_w, pose_w, tid, w0);
    load_w_row(lip_w, pose_w, tid + 256, w1);
#pragma unroll
    for (int k = 0; k < 26; ++k) {
        float q0 = 0.f, q1 = 0.f;
#pragma unroll
        for (int m = 0; m < 26; ++m) {
            if (m <= k) {
                const float r = Rinv[m][k];
                q0 = fmaf(w0[m], r, q0);
                q1 = fmaf(w1[m], r, q1);
            }
        }
        qt[k * 512 + tid]       = q0;
        qt[k * 512 + tid + 256] = q1;
    }
}

// ---------------------------------------------------------------------------
// out[B][512] = input[B][26] @ qt^T   (qt is [26][512])
// Block = 256 threads handles 32 rows x 512 cols. Q fragment (26 x float4)
// in registers; input tile staged in LDS (broadcast reads); float4 stores.
// ---------------------------------------------------------------------------

__global__ __launch_bounds__(256) void out_gemm(const float* __restrict__ in,
                                                const float* __restrict__ qt,
                                                float* __restrict__ out) {
    __shared__ float xs[832];             // 32 rows x 26, linear
    const int tid = threadIdx.x;
    const long base = (long)blockIdx.x * 32;

    // Cooperative float4 load of the 32x26 input tile (832 floats = 208 f4).
    const float4* ip4 = reinterpret_cast<const float4*>(in + base * 26);
    if (tid < 208) reinterpret_cast<float4*>(xs)[tid] = ip4[tid];

    const int cg = tid & 127;             // column group: cols 4*cg .. 4*cg+3
    const int rh = tid >> 7;              // row half: 0 or 1

    float4 qf[26];
#pragma unroll
    for (int k = 0; k < 26; ++k)
        qf[k] = *reinterpret_cast<const float4*>(qt + k * 512 + cg * 4);
    __syncthreads();

    float* op = out + (base + (long)rh * 16) * 512 + cg * 4;
#pragma unroll
    for (int r = 0; r < 16; ++r) {
        const float* xr = xs + (rh * 16 + r) * 26;
        float ax = 0.f, ay = 0.f, az = 0.f, aw = 0.f;
#pragma unroll
        for (int k = 0; k < 26; ++k) {
            const float x = xr[k];
            ax = fmaf(x, qf[k].x, ax);
            ay = fmaf(x, qf[k].y, ay);
            az = fmaf(x, qf[k].z, az);
            aw = fmaf(x, qf[k].w, aw);
        }
        *reinterpret_cast<float4*>(op + (long)r * 512) = make_float4(ax, ay, az, aw);
    }
}

// ---------------------------------------------------------------------------

extern "C" void kernel_launch(void* const* d_in, const int* in_sizes, int n_in,
                              void* d_out, int out_size, void* d_ws, size_t ws_size,
                              hipStream_t stream) {
    const float* input  = (const float*)d_in[0];   // (B, 26)
    const float* pose_w = (const float*)d_in[1];   // (512, 6)
    const float* lip_w  = (const float*)d_in[2];   // (512, 20)
    float* out = (float*)d_out;                    // (B, 512)
    float* qt  = (float*)d_ws;                     // Q^T as [26][512] f32

    const int B = in_sizes[0] / 26;

    qr_kernel<<<1, 256, 0, stream>>>(pose_w, lip_w, qt);
    out_gemm<<<(B + 31) / 32, 256, 0, stream>>>(input, qt, out);
}

// Round 4
// 100.916 us; speedup vs baseline: 2.3663x; 1.2240x over previous
//
#include <hip/hip_runtime.h>
#include <hip/hip_bf16.h>

#define EPSV 1e-8f

typedef float f32x4 __attribute__((ext_vector_type(4)));

// ---------------------------------------------------------------------------
// Householder QR of W = [weight | pose_weight] + EPS  (512 x 26), replicating
// LAPACK sgeqrf sign conventions (beta = -sign(alpha)*norm), then
// Q = W * R^{-1}, stored transposed as qt[26][512] in workspace.
//
// 4-wave register-resident core: 256 threads; thread t owns rows t and t+256
// (a[2][26] = 52 VGPRs, all indices compile-time static via template<int J>
// recursion). Per step:
//   - per-thread partials for {sigma, S_c} over its 2 rows
//   - 6-stage __shfl_xor butterfly within each wave (low VGPR pressure ->
//     the 26 independent chains pipeline)
//   - lane 0 of each wave publishes 26 sums to LDS; ONE barrier
//     (parity double-buffered buffers -> no second barrier)
//   - every thread sums the 4 wave partials and applies the rank-1 update
// ---------------------------------------------------------------------------

__device__ __forceinline__ void load_w_row(const float* __restrict__ lip_w,
                                           const float* __restrict__ pose_w,
                                           int row, float* w) {
    const float4* lp4 = reinterpret_cast<const float4*>(lip_w + row * 20);
    float4 t0 = lp4[0], t1 = lp4[1], t2 = lp4[2], t3 = lp4[3], t4 = lp4[4];
    const float2* pp2 = reinterpret_cast<const float2*>(pose_w + row * 6);
    float2 u0 = pp2[0], u1 = pp2[1], u2 = pp2[2];
    w[0]  = t0.x + EPSV; w[1]  = t0.y + EPSV; w[2]  = t0.z + EPSV; w[3]  = t0.w + EPSV;
    w[4]  = t1.x + EPSV; w[5]  = t1.y + EPSV; w[6]  = t1.z + EPSV; w[7]  = t1.w + EPSV;
    w[8]  = t2.x + EPSV; w[9]  = t2.y + EPSV; w[10] = t2.z + EPSV; w[11] = t2.w + EPSV;
    w[12] = t3.x + EPSV; w[13] = t3.y + EPSV; w[14] = t3.z + EPSV; w[15] = t3.w + EPSV;
    w[16] = t4.x + EPSV; w[17] = t4.y + EPSV; w[18] = t4.z + EPSV; w[19] = t4.w + EPSV;
    w[20] = u0.x + EPSV; w[21] = u0.y + EPSV;
    w[22] = u1.x + EPSV; w[23] = u1.y + EPSV;
    w[24] = u2.x + EPSV; w[25] = u2.y + EPSV;
}

template<int J>
__device__ __forceinline__ void qr_step4(float (&a)[2][26], const int tid,
                                         const int lane, const int wid,
                                         float (*wavePart)[4][26],   // [2][4][26]
                                         float (*rowj)[26]) {        // [2][26]
    const int buf = J & 1;

    // Pivot row publish (thread J; its registers are current in program order).
    if (tid == J) {
#pragma unroll
        for (int c = 0; c < 26; ++c)
            if (c >= J) rowj[buf][c] = a[0][c];
    }

    // Per-thread partials over rows {tid, tid+256}. Row tid+256 > 25 >= J
    // is always inside the reflector; row tid masks on tid vs J.
    float p[26];
    const float x0s = (tid >= J) ? a[0][J] : 0.f;
    const float x0d = (tid >  J) ? a[0][J] : 0.f;
    const float x1  = a[1][J];
    p[J] = fmaf(x1, x1, x0s * x0s);
#pragma unroll
    for (int c = 0; c < 26; ++c)
        if (c > J) p[c] = fmaf(x1, a[1][c], x0d * a[0][c]);

    // Intra-wave butterfly (26-J independent chains, 6 stages).
#pragma unroll
    for (int o = 32; o > 0; o >>= 1) {
#pragma unroll
        for (int c = 0; c < 26; ++c)
            if (c >= J) p[c] += __shfl_xor(p[c], o);
    }

    // Wave publish (static indices; single lane).
    if (lane == 0) {
#pragma unroll
        for (int c = 0; c < 26; ++c)
            if (c >= J) wavePart[buf][wid][c] = p[c];
    }
    __syncthreads();

    // Cross-wave totals + scalars (replicated; reads are LDS broadcasts).
    const float sigma = wavePart[buf][0][J] + wavePart[buf][1][J]
                      + wavePart[buf][2][J] + wavePart[buf][3][J];
    const float alpha  = rowj[buf][J];
    const float normx  = sqrtf(sigma);
    const float beta   = (alpha >= 0.f) ? -normx : normx;    // LAPACK slarfg
    const float tau    = (beta - alpha) / beta;
    const float rdenom = 1.f / (alpha - beta);               // |alpha-beta| >= norm

    // tau * v_i per owned row (v_pivot = 1; rows < J masked to 0).
    const float t0 = (tid == J) ? tau
                   : ((tid > J) ? tau * rdenom * a[0][J] : 0.f);
    const float t1 = tau * rdenom * x1;

    // Rank-1 update: a_ic -= (tau v_i) * d_c,  d_c = a_Jc + S_c/(alpha-beta).
#pragma unroll
    for (int c = 0; c < 26; ++c) {
        if (c > J) {
            const float S = wavePart[buf][0][c] + wavePart[buf][1][c]
                          + wavePart[buf][2][c] + wavePart[buf][3][c];
            const float dc = fmaf(S, rdenom, rowj[buf][c]);
            a[0][c] = fmaf(-t0, dc, a[0][c]);
            a[1][c] = fmaf(-t1, dc, a[1][c]);
        }
    }
    if (tid == J) a[0][J] = beta;                            // R diagonal
}

template<int J> struct Steps {
    static __device__ __forceinline__ void run(float (&a)[2][26], int tid, int lane,
                                               int wid, float (*wp)[4][26],
                                               float (*rj)[26]) {
        qr_step4<J>(a, tid, lane, wid, wp, rj);
        Steps<J + 1>::run(a, tid, lane, wid, wp, rj);
    }
};
template<> struct Steps<26> {
    static __device__ __forceinline__ void run(float (&)[2][26], int, int, int,
                                               float (*)[4][26], float (*)[26]) {}
};

__global__ __launch_bounds__(256) void qr_kernel(const float* __restrict__ pose_w,
                                                 const float* __restrict__ lip_w,
                                                 float* __restrict__ qt) {
    __shared__ float wavePart[2][4][26];
    __shared__ float rowj[2][26];
    __shared__ float Rlds[26][27];
    __shared__ float Rinv[26][27];

    const int tid  = threadIdx.x;
    const int lane = tid & 63;
    const int wid  = tid >> 6;

    float a[2][26];
    load_w_row(lip_w, pose_w, tid,       a[0]);
    load_w_row(lip_w, pose_w, tid + 256, a[1]);

    Steps<0>::run(a, tid, lane, wid, wavePart, rowj);

    // R row j is in thread j, slot 0 (rows < J have tau*v = 0 in later steps).
    if (tid < 26) {
#pragma unroll
        for (int c = 0; c < 26; ++c)
            if (c >= tid) Rlds[tid][c] = a[0][c];
    }
    __syncthreads();

    // Back-substitution, fully static-indexed: thread cc solves column cc of
    // R^{-1} in registers (ri[m] valid for m <= cc; garbage above, unused).
    if (tid < 26) {
        float ri[26];
#pragma unroll
        for (int k = 25; k >= 0; --k) {
            float s = (k == tid) ? 1.f : 0.f;
#pragma unroll
            for (int m = 25; m > k; --m)
                if (m <= tid) s = fmaf(-Rlds[k][m], ri[m], s);
            ri[k] = s / Rlds[k][k];
        }
#pragma unroll
        for (int k = 0; k < 26; ++k)
            if (k <= tid) Rinv[k][tid] = ri[k];
    }
    __syncthreads();

    // Q = W * Rinv, stored transposed: qt[k*512 + i] = Q[i][k].
    // 256 threads x 2 rows; Rinv upper-triangular => m <= k.
    float w0[26], w1[26];
    load_w_row(lip_w, pose_w, tid,       w0);
    load_w_row(lip_w, pose_w, tid + 256, w1);
#pragma unroll
    for (int k = 0; k < 26; ++k) {
        float q0 = 0.f, q1 = 0.f;
#pragma unroll
        for (int m = 0; m < 26; ++m) {
            if (m <= k) {
                const float r = Rinv[m][k];
                q0 = fmaf(w0[m], r, q0);
                q1 = fmaf(w1[m], r, q1);
            }
        }
        qt[k * 512 + tid]       = q0;
        qt[k * 512 + tid + 256] = q1;
    }
}

// ---------------------------------------------------------------------------
// out[B][512] = input[B][26] @ qt^T   (qt is [26][512])
// Block = 256 threads handles 32 rows x 512 cols. Q fragment (26 x float4)
// in registers; input tile staged in LDS (broadcast reads); nontemporal
// float4 stores (268 MB streaming output, never re-read).
// ---------------------------------------------------------------------------

__global__ __launch_bounds__(256) void out_gemm(const float* __restrict__ in,
                                                const float* __restrict__ qt,
                                                float* __restrict__ out) {
    __shared__ float xs[832];             // 32 rows x 26, linear
    const int tid = threadIdx.x;
    const long base = (long)blockIdx.x * 32;

    // Cooperative float4 load of the 32x26 input tile (832 floats = 208 f4).
    const float4* ip4 = reinterpret_cast<const float4*>(in + base * 26);
    if (tid < 208) reinterpret_cast<float4*>(xs)[tid] = ip4[tid];

    const int cg = tid & 127;             // column group: cols 4*cg .. 4*cg+3
    const int rh = tid >> 7;              // row half: 0 or 1

    float4 qf[26];
#pragma unroll
    for (int k = 0; k < 26; ++k)
        qf[k] = *reinterpret_cast<const float4*>(qt + k * 512 + cg * 4);
    __syncthreads();

    float* op = out + (base + (long)rh * 16) * 512 + cg * 4;
#pragma unroll
    for (int r = 0; r < 16; ++r) {
        const float* xr = xs + (rh * 16 + r) * 26;
        float ax = 0.f, ay = 0.f, az = 0.f, aw = 0.f;
#pragma unroll
        for (int k = 0; k < 26; ++k) {
            const float x = xr[k];
            ax = fmaf(x, qf[k].x, ax);
            ay = fmaf(x, qf[k].y, ay);
            az = fmaf(x, qf[k].z, az);
            aw = fmaf(x, qf[k].w, aw);
        }
        f32x4 o;
        o.x = ax; o.y = ay; o.z = az; o.w = aw;
        __builtin_nontemporal_store(o, reinterpret_cast<f32x4*>(op + (long)r * 512));
    }
}

// ---------------------------------------------------------------------------

extern "C" void kernel_launch(void* const* d_in, const int* in_sizes, int n_in,
                              void* d_out, int out_size, void* d_ws, size_t ws_size,
                              hipStream_t stream) {
    const float* input  = (const float*)d_in[0];   // (B, 26)
    const float* pose_w = (const float*)d_in[1];   // (512, 6)
    const float* lip_w  = (const float*)d_in[2];   // (512, 20)
    float* out = (float*)d_out;                    // (B, 512)
    float* qt  = (float*)d_ws;                     // Q^T as [26][512] f32

    const int B = in_sizes[0] / 26;

    qr_kernel<<<1, 256, 0, stream>>>(pose_w, lip_w, qt);
    out_gemm<<<(B + 31) / 32, 256, 0, stream>>>(input, qt, out);
}

// Round 5
// 82.450 us; speedup vs baseline: 2.8962x; 1.2240x over previous
//
#include <hip/hip_runtime.h>
#include <hip/hip_bf16.h>

#define EPSV 1e-8f
#define WSTRIDE 516   // floats; %4==0 (b128-aligned columns), %32==4 (bank spread)

typedef float f32x4 __attribute__((ext_vector_type(4)));

__device__ __forceinline__ float rdlane(float v, int l) {
    return __int_as_float(__builtin_amdgcn_readlane(__float_as_int(v), l));
}

__device__ __forceinline__ void load_w_row(const float* __restrict__ lip_w,
                                           const float* __restrict__ pose_w,
                                           int row, float* w) {
    const float4* lp4 = reinterpret_cast<const float4*>(lip_w + row * 20);
    float4 t0 = lp4[0], t1 = lp4[1], t2 = lp4[2], t3 = lp4[3], t4 = lp4[4];
    const float2* pp2 = reinterpret_cast<const float2*>(pose_w + row * 6);
    float2 u0 = pp2[0], u1 = pp2[1], u2 = pp2[2];
    w[0]  = t0.x + EPSV; w[1]  = t0.y + EPSV; w[2]  = t0.z + EPSV; w[3]  = t0.w + EPSV;
    w[4]  = t1.x + EPSV; w[5]  = t1.y + EPSV; w[6]  = t1.z + EPSV; w[7]  = t1.w + EPSV;
    w[8]  = t2.x + EPSV; w[9]  = t2.y + EPSV; w[10] = t2.z + EPSV; w[11] = t2.w + EPSV;
    w[12] = t3.x + EPSV; w[13] = t3.y + EPSV; w[14] = t3.z + EPSV; w[15] = t3.w + EPSV;
    w[16] = t4.x + EPSV; w[17] = t4.y + EPSV; w[18] = t4.z + EPSV; w[19] = t4.w + EPSV;
    w[20] = u0.x + EPSV; w[21] = u0.y + EPSV;
    w[22] = u1.x + EPSV; w[23] = u1.y + EPSV;
    w[24] = u2.x + EPSV; w[25] = u2.y + EPSV;
}

// ---------------------------------------------------------------------------
// Collapsed Householder step J on the 26x26 pivot block.
// Lane c owns column c of P (pivot rows) and R. All cross-lane data comes
// from lane J via v_readlane (column J of P/R lives in lane J's registers).
// sigma_J = G[J,J] - sum_{i<J} R[i,J]^2
// S_c     = G[J,c] - sum_{i<J} R[i,J] R[i,c] - alpha * P[J,c]
// ---------------------------------------------------------------------------
template<int J>
struct QRStep {
    static __device__ __forceinline__ void run(float (&P)[26], float (&R)[26],
                                               const float (&Gr)[26], const int tid) {
        float sig = rdlane(Gr[J], J);          // G[J][J]
        float dot = 0.f;                        // sum_{i<J} R[i][J] * R[i][c]
#pragma unroll
        for (int i = 0; i < 26; ++i) {
            if (i < J) {
                const float rij = rdlane(R[i], J);
                sig = fmaf(-rij, rij, sig);
                dot = fmaf(rij, R[i], dot);
            }
        }
        const float alpha  = rdlane(P[J], J);
        const float S      = Gr[J] - dot - alpha * P[J];
        const float normx  = sqrtf(sig);
        const float beta   = (alpha >= 0.f) ? -normx : normx;   // LAPACK slarfg
        const float tau    = (beta - alpha) / beta;
        const float rdenom = 1.f / (alpha - beta);
        const float dc     = fmaf(S, rdenom, P[J]);
        R[J] = (tid == J) ? beta : fmaf(-tau, dc, P[J]);        // R row J
        const float trd = tau * rdenom;
#pragma unroll
        for (int i = 0; i < 26; ++i) {
            if (i > J) {
                const float pij = rdlane(P[i], J);              // P[i][J]
                P[i] = fmaf(-(trd * pij), dc, P[i]);
            }
        }
    }
};

template<int J> struct QRSteps {
    static __device__ __forceinline__ void run(float (&P)[26], float (&R)[26],
                                               const float (&Gr)[26], int tid) {
        QRStep<J>::run(P, R, Gr, tid);
        QRSteps<J + 1>::run(P, R, Gr, tid);
    }
};
template<> struct QRSteps<26> {
    static __device__ __forceinline__ void run(float (&)[26], float (&)[26],
                                               const float (&)[26], int) {}
};

__global__ __launch_bounds__(512) void qr_kernel(const float* __restrict__ pose_w,
                                                 const float* __restrict__ lip_w,
                                                 float* __restrict__ qt) {
    __shared__ float Wc[26 * WSTRIDE];    // W+EPS, column-major
    __shared__ float G[26 * 27 + 8];      // Gram (both triangles)
    __shared__ float Rlds[26][27];
    __shared__ float Rinv[26][27];

    const int tid = threadIdx.x;

    // ---- Stage 1: load row tid, scatter to column-major LDS --------------
    {
        float w[26];
        load_w_row(lip_w, pose_w, tid, w);
#pragma unroll
        for (int c = 0; c < 26; ++c) Wc[c * WSTRIDE + tid] = w[c];
    }
    __syncthreads();

    // ---- Stage 2: Gram G = W^T W via 3x3 tiles (45 threads, one wave) ----
    if (tid < 45) {
        int tm = 0, rem = tid;
        while (rem >= 9 - tm) { rem -= 9 - tm; ++tm; }
        const int tn = tm + rem;
        const int ra = (tm * 3 > 23) ? 23 : tm * 3;   // clamp: rows ra..ra+2 <= 25
        const int ca = (tn * 3 > 23) ? 23 : tn * 3;   // (overlap tiles write equal values)
        const f32x4* A0 = reinterpret_cast<const f32x4*>(&Wc[(ra + 0) * WSTRIDE]);
        const f32x4* A1 = reinterpret_cast<const f32x4*>(&Wc[(ra + 1) * WSTRIDE]);
        const f32x4* A2 = reinterpret_cast<const f32x4*>(&Wc[(ra + 2) * WSTRIDE]);
        const f32x4* B0 = reinterpret_cast<const f32x4*>(&Wc[(ca + 0) * WSTRIDE]);
        const f32x4* B1 = reinterpret_cast<const f32x4*>(&Wc[(ca + 1) * WSTRIDE]);
        const f32x4* B2 = reinterpret_cast<const f32x4*>(&Wc[(ca + 2) * WSTRIDE]);
        float acc[3][3] = {{0.f, 0.f, 0.f}, {0.f, 0.f, 0.f}, {0.f, 0.f, 0.f}};
#pragma unroll 4
        for (int i = 0; i < 128; ++i) {
            const f32x4 av[3] = {A0[i], A1[i], A2[i]};
            const f32x4 bv[3] = {B0[i], B1[i], B2[i]};
#pragma unroll
            for (int r = 0; r < 3; ++r) {
#pragma unroll
                for (int c = 0; c < 3; ++c) {
                    acc[r][c] = fmaf(av[r].x, bv[c].x, acc[r][c]);
                    acc[r][c] = fmaf(av[r].y, bv[c].y, acc[r][c]);
                    acc[r][c] = fmaf(av[r].z, bv[c].z, acc[r][c]);
                    acc[r][c] = fmaf(av[r].w, bv[c].w, acc[r][c]);
                }
            }
        }
#pragma unroll
        for (int r = 0; r < 3; ++r) {
#pragma unroll
            for (int c = 0; c < 3; ++c) {
                G[(ra + r) * 27 + (ca + c)] = acc[r][c];
                G[(ca + c) * 27 + (ra + r)] = acc[r][c];
            }
        }
    }
    __syncthreads();

    // ---- Stage 3: 26-step collapsed Householder + back-sub (wave 0) -----
    if (tid < 64) {
        const int cc = (tid < 26) ? tid : 25;   // clamp for safe addressing
        float P[26], R[26], Gr[26];
        {   // column cc, rows 0..25, via 7 b128 reads (stride WSTRIDE%4==0)
            const f32x4* pc = reinterpret_cast<const f32x4*>(&Wc[cc * WSTRIDE]);
            const f32x4 q0 = pc[0], q1 = pc[1], q2 = pc[2], q3 = pc[3],
                        q4 = pc[4], q5 = pc[5], q6 = pc[6];
            P[0]=q0.x;  P[1]=q0.y;  P[2]=q0.z;  P[3]=q0.w;
            P[4]=q1.x;  P[5]=q1.y;  P[6]=q1.z;  P[7]=q1.w;
            P[8]=q2.x;  P[9]=q2.y;  P[10]=q2.z; P[11]=q2.w;
            P[12]=q3.x; P[13]=q3.y; P[14]=q3.z; P[15]=q3.w;
            P[16]=q4.x; P[17]=q4.y; P[18]=q4.z; P[19]=q4.w;
            P[20]=q5.x; P[21]=q5.y; P[22]=q5.z; P[23]=q5.w;
            P[24]=q6.x; P[25]=q6.y;
        }
#pragma unroll
        for (int j = 0; j < 26; ++j) Gr[j] = G[j * 27 + cc];

        QRSteps<0>::run(P, R, Gr, tid);

        // Stage R rows for back-substitution (lane c holds column c).
        if (tid < 26) {
#pragma unroll
            for (int i = 0; i < 26; ++i)
                if (i <= tid) Rlds[i][tid] = R[i];
        }
        // Same wave: LDS writes ordered before reads below (lgkmcnt).

        // Back-substitution: thread cc solves column cc of R^{-1}.
        if (tid < 26) {
            float ri[26];
#pragma unroll
            for (int k = 25; k >= 0; --k) {
                float s = (k == tid) ? 1.f : 0.f;
#pragma unroll
                for (int m = 25; m > k; --m)
                    if (m <= tid) s = fmaf(-Rlds[k][m], ri[m], s);
                ri[k] = s / Rlds[k][k];
            }
#pragma unroll
            for (int k = 0; k < 26; ++k)
                if (k <= tid) Rinv[k][tid] = ri[k];
        }
    }
    __syncthreads();

    // ---- Stage 4: Q = W * Rinv, transposed store qt[k*512 + row] ---------
    // 128 threads x 4 rows: Rinv's 351 broadcast LDS reads issued by 2 waves
    // only; fma cost shared across the 4 rows.
    if (tid < 128) {
        float w0[26], w1[26], w2[26], w3[26];
        load_w_row(lip_w, pose_w, tid,       w0);
        load_w_row(lip_w, pose_w, tid + 128, w1);
        load_w_row(lip_w, pose_w, tid + 256, w2);
        load_w_row(lip_w, pose_w, tid + 384, w3);
#pragma unroll
        for (int k = 0; k < 26; ++k) {
            float q0 = 0.f, q1 = 0.f, q2 = 0.f, q3 = 0.f;
#pragma unroll
            for (int m = 0; m < 26; ++m) {
                if (m <= k) {
                    const float r = Rinv[m][k];
                    q0 = fmaf(w0[m], r, q0);
                    q1 = fmaf(w1[m], r, q1);
                    q2 = fmaf(w2[m], r, q2);
                    q3 = fmaf(w3[m], r, q3);
                }
            }
            float* qk = qt + k * 512 + tid;
            qk[0]   = q0;
            qk[128] = q1;
            qk[256] = q2;
            qk[384] = q3;
        }
    }
}

// ---------------------------------------------------------------------------
// out[B][512] = input[B][26] @ qt^T   (qt is [26][512])
// Block = 256 threads handles 32 rows x 512 cols. Q fragment (26 x float4)
// in registers; input tile staged in LDS (broadcast reads); nontemporal
// float4 stores (268 MB streaming output, never re-read).
// ---------------------------------------------------------------------------

__global__ __launch_bounds__(256) void out_gemm(const float* __restrict__ in,
                                                const float* __restrict__ qt,
                                                float* __restrict__ out) {
    __shared__ float xs[832];             // 32 rows x 26, linear
    const int tid = threadIdx.x;
    const long base = (long)blockIdx.x * 32;

    // Cooperative float4 load of the 32x26 input tile (832 floats = 208 f4).
    const float4* ip4 = reinterpret_cast<const float4*>(in + base * 26);
    if (tid < 208) reinterpret_cast<float4*>(xs)[tid] = ip4[tid];

    const int cg = tid & 127;             // column group: cols 4*cg .. 4*cg+3
    const int rh = tid >> 7;              // row half: 0 or 1

    float4 qf[26];
#pragma unroll
    for (int k = 0; k < 26; ++k)
        qf[k] = *reinterpret_cast<const float4*>(qt + k * 512 + cg * 4);
    __syncthreads();

    float* op = out + (base + (long)rh * 16) * 512 + cg * 4;
#pragma unroll
    for (int r = 0; r < 16; ++r) {
        const float* xr = xs + (rh * 16 + r) * 26;
        float ax = 0.f, ay = 0.f, az = 0.f, aw = 0.f;
#pragma unroll
        for (int k = 0; k < 26; ++k) {
            const float x = xr[k];
            ax = fmaf(x, qf[k].x, ax);
            ay = fmaf(x, qf[k].y, ay);
            az = fmaf(x, qf[k].z, az);
            aw = fmaf(x, qf[k].w, aw);
        }
        f32x4 o;
        o.x = ax; o.y = ay; o.z = az; o.w = aw;
        __builtin_nontemporal_store(o, reinterpret_cast<f32x4*>(op + (long)r * 512));
    }
}

// ---------------------------------------------------------------------------

extern "C" void kernel_launch(void* const* d_in, const int* in_sizes, int n_in,
                              void* d_out, int out_size, void* d_ws, size_t ws_size,
                              hipStream_t stream) {
    const float* input  = (const float*)d_in[0];   // (B, 26)
    const float* pose_w = (const float*)d_in[1];   // (512, 6)
    const float* lip_w  = (const float*)d_in[2];   // (512, 20)
    float* out = (float*)d_out;                    // (B, 512)
    float* qt  = (float*)d_ws;                     // Q^T as [26][512] f32

    const int B = in_sizes[0] / 26;

    qr_kernel<<<1, 512, 0, stream>>>(pose_w, lip_w, qt);
    out_gemm<<<(B + 31) / 32, 256, 0, stream>>>(input, qt, out);
}

// Round 6
// 72.758 us; speedup vs baseline: 3.2820x; 1.1332x over previous
//
#include <hip/hip_runtime.h>
#include <hip/hip_bf16.h>

#define EPSV 1e-8f
#define WSTRIDE 516   // floats; %4==0 (b128-aligned columns), %32==4 (bank spread)

typedef float f32x4 __attribute__((ext_vector_type(4)));

__device__ __forceinline__ float rdlane(float v, int l) {
    return __int_as_float(__builtin_amdgcn_readlane(__float_as_int(v), l));
}

__device__ __forceinline__ void load_w_row(const float* __restrict__ lip_w,
                                           const float* __restrict__ pose_w,
                                           int row, float* w) {
    const float4* lp4 = reinterpret_cast<const float4*>(lip_w + row * 20);
    float4 t0 = lp4[0], t1 = lp4[1], t2 = lp4[2], t3 = lp4[3], t4 = lp4[4];
    const float2* pp2 = reinterpret_cast<const float2*>(pose_w + row * 6);
    float2 u0 = pp2[0], u1 = pp2[1], u2 = pp2[2];
    w[0]  = t0.x + EPSV; w[1]  = t0.y + EPSV; w[2]  = t0.z + EPSV; w[3]  = t0.w + EPSV;
    w[4]  = t1.x + EPSV; w[5]  = t1.y + EPSV; w[6]  = t1.z + EPSV; w[7]  = t1.w + EPSV;
    w[8]  = t2.x + EPSV; w[9]  = t2.y + EPSV; w[10] = t2.z + EPSV; w[11] = t2.w + EPSV;
    w[12] = t3.x + EPSV; w[13] = t3.y + EPSV; w[14] = t3.z + EPSV; w[15] = t3.w + EPSV;
    w[16] = t4.x + EPSV; w[17] = t4.y + EPSV; w[18] = t4.z + EPSV; w[19] = t4.w + EPSV;
    w[20] = u0.x + EPSV; w[21] = u0.y + EPSV;
    w[22] = u1.x + EPSV; w[23] = u1.y + EPSV;
    w[24] = u2.x + EPSV; w[25] = u2.y + EPSV;
}

// ---------------------------------------------------------------------------
// Collapsed Householder step J on the 26x26 pivot block (Gram invariant).
// Lane c owns column c of P (pivot rows) and R; cross-lane via v_readlane.
// ---------------------------------------------------------------------------
template<int J>
struct QRStep {
    static __device__ __forceinline__ void run(float (&P)[26], float (&R)[26],
                                               const float (&Gr)[26], const int tid) {
        float sig = rdlane(Gr[J], J);          // G[J][J]
        float dot = 0.f;                        // sum_{i<J} R[i][J] * R[i][c]
#pragma unroll
        for (int i = 0; i < 26; ++i) {
            if (i < J) {
                const float rij = rdlane(R[i], J);
                sig = fmaf(-rij, rij, sig);
                dot = fmaf(rij, R[i], dot);
            }
        }
        const float alpha  = rdlane(P[J], J);
        const float S      = Gr[J] - dot - alpha * P[J];
        const float normx  = sqrtf(sig);
        const float beta   = (alpha >= 0.f) ? -normx : normx;   // LAPACK slarfg
        const float tau    = (beta - alpha) / beta;
        const float rdenom = 1.f / (alpha - beta);
        const float dc     = fmaf(S, rdenom, P[J]);
        R[J] = (tid == J) ? beta : fmaf(-tau, dc, P[J]);        // R row J
        const float trd = tau * rdenom;
#pragma unroll
        for (int i = 0; i < 26; ++i) {
            if (i > J) {
                const float pij = rdlane(P[i], J);              // P[i][J]
                P[i] = fmaf(-(trd * pij), dc, P[i]);
            }
        }
    }
};

template<int J> struct QRSteps {
    static __device__ __forceinline__ void run(float (&P)[26], float (&R)[26],
                                               const float (&Gr)[26], int tid) {
        QRStep<J>::run(P, R, Gr, tid);
        QRSteps<J + 1>::run(P, R, Gr, tid);
    }
};
template<> struct QRSteps<26> {
    static __device__ __forceinline__ void run(float (&)[26], float (&)[26],
                                               const float (&)[26], int) {}
};

__global__ __launch_bounds__(512) void qr_kernel(const float* __restrict__ pose_w,
                                                 const float* __restrict__ lip_w,
                                                 float* __restrict__ qt) {
    __shared__ float Wc[26 * WSTRIDE];    // W+EPS, column-major
    __shared__ float Gp[8][26][27];       // per-wave partial Gram
    __shared__ float G[26 * 27 + 8];      // Gram (both triangles)
    __shared__ float Rlds[26][27];
    __shared__ float Rinv[26][27];

    const int tid  = threadIdx.x;
    const int lane = tid & 63;
    const int wid  = tid >> 6;

    // ---- Stage 1: load row tid, scatter to column-major LDS --------------
    {
        float w[26];
        load_w_row(lip_w, pose_w, tid, w);
#pragma unroll
        for (int c = 0; c < 26; ++c) Wc[c * WSTRIDE + tid] = w[c];
    }
    __syncthreads();

    // ---- Stage 2: Gram G = W^T W, 8-wave parallel over row chunks --------
    // Wave w covers rows 64w..64w+63 (f32x4 iters 16w..16w+15); 45 active
    // lanes per wave each own a 3x3 tile of the 26x26 output.
    if (lane < 45) {
        int tm = 0, rem = lane;
        while (rem >= 9 - tm) { rem -= 9 - tm; ++tm; }
        const int tn = tm + rem;
        const int ra = (tm * 3 > 23) ? 23 : tm * 3;   // clamped tiles overlap but
        const int ca = (tn * 3 > 23) ? 23 : tn * 3;   // write identical values
        const f32x4* A0 = reinterpret_cast<const f32x4*>(&Wc[(ra + 0) * WSTRIDE]);
        const f32x4* A1 = reinterpret_cast<const f32x4*>(&Wc[(ra + 1) * WSTRIDE]);
        const f32x4* A2 = reinterpret_cast<const f32x4*>(&Wc[(ra + 2) * WSTRIDE]);
        const f32x4* B0 = reinterpret_cast<const f32x4*>(&Wc[(ca + 0) * WSTRIDE]);
        const f32x4* B1 = reinterpret_cast<const f32x4*>(&Wc[(ca + 1) * WSTRIDE]);
        const f32x4* B2 = reinterpret_cast<const f32x4*>(&Wc[(ca + 2) * WSTRIDE]);
        float acc[3][3] = {{0.f, 0.f, 0.f}, {0.f, 0.f, 0.f}, {0.f, 0.f, 0.f}};
        const int i0 = 16 * wid;
#pragma unroll 4
        for (int ii = 0; ii < 16; ++ii) {
            const int i = i0 + ii;
            const f32x4 av[3] = {A0[i], A1[i], A2[i]};
            const f32x4 bv[3] = {B0[i], B1[i], B2[i]};
#pragma unroll
            for (int r = 0; r < 3; ++r) {
#pragma unroll
                for (int c = 0; c < 3; ++c) {
                    acc[r][c] = fmaf(av[r].x, bv[c].x, acc[r][c]);
                    acc[r][c] = fmaf(av[r].y, bv[c].y, acc[r][c]);
                    acc[r][c] = fmaf(av[r].z, bv[c].z, acc[r][c]);
                    acc[r][c] = fmaf(av[r].w, bv[c].w, acc[r][c]);
                }
            }
        }
#pragma unroll
        for (int r = 0; r < 3; ++r) {
#pragma unroll
            for (int c = 0; c < 3; ++c) {
                Gp[wid][ra + r][ca + c] = acc[r][c];
                Gp[wid][ca + c][ra + r] = acc[r][c];
            }
        }
    }
    __syncthreads();

    // Reduce the 8 partials: thread t < 351 owns upper-tri pair (r,c).
    if (tid < 351) {
        int r = 0, t = tid;
        while (t >= 26 - r) { t -= 26 - r; ++r; }
        const int c = r + t;
        float s = 0.f;
#pragma unroll
        for (int w8 = 0; w8 < 8; ++w8) s += Gp[w8][r][c];
        G[r * 27 + c] = s;
        G[c * 27 + r] = s;
    }
    __syncthreads();

    // ---- Stage 3: 26-step collapsed Householder + back-sub (wave 0) -----
    if (tid < 64) {
        const int cc = (tid < 26) ? tid : 25;   // clamp for safe addressing
        float P[26], R[26], Gr[26];
        {   // column cc, rows 0..25, via 7 b128 reads (stride WSTRIDE%4==0)
            const f32x4* pc = reinterpret_cast<const f32x4*>(&Wc[cc * WSTRIDE]);
            const f32x4 q0 = pc[0], q1 = pc[1], q2 = pc[2], q3 = pc[3],
                        q4 = pc[4], q5 = pc[5], q6 = pc[6];
            P[0]=q0.x;  P[1]=q0.y;  P[2]=q0.z;  P[3]=q0.w;
            P[4]=q1.x;  P[5]=q1.y;  P[6]=q1.z;  P[7]=q1.w;
            P[8]=q2.x;  P[9]=q2.y;  P[10]=q2.z; P[11]=q2.w;
            P[12]=q3.x; P[13]=q3.y; P[14]=q3.z; P[15]=q3.w;
            P[16]=q4.x; P[17]=q4.y; P[18]=q4.z; P[19]=q4.w;
            P[20]=q5.x; P[21]=q5.y; P[22]=q5.z; P[23]=q5.w;
            P[24]=q6.x; P[25]=q6.y;
        }
#pragma unroll
        for (int j = 0; j < 26; ++j) Gr[j] = G[j * 27 + cc];

        QRSteps<0>::run(P, R, Gr, tid);

        // Stage R (lane c holds column c); same-wave write->read is ordered.
        if (tid < 26) {
#pragma unroll
            for (int i = 0; i < 26; ++i)
                if (i <= tid) Rlds[i][tid] = R[i];
        }

        // Back-substitution: thread cc solves column cc of R^{-1}.
        if (tid < 26) {
            float ri[26];
#pragma unroll
            for (int k = 25; k >= 0; --k) {
                float s = (k == tid) ? 1.f : 0.f;
#pragma unroll
                for (int m = 25; m > k; --m)
                    if (m <= tid) s = fmaf(-Rlds[k][m], ri[m], s);
                ri[k] = s / Rlds[k][k];
            }
#pragma unroll
            for (int k = 0; k < 26; ++k)
                if (k <= tid) Rinv[k][tid] = ri[k];
        }
    }
    __syncthreads();

    // ---- Stage 4: Q = W * Rinv, transposed store qt[k*512 + row] ---------
    if (tid < 128) {
        float w0[26], w1[26], w2[26], w3[26];
        load_w_row(lip_w, pose_w, tid,       w0);
        load_w_row(lip_w, pose_w, tid + 128, w1);
        load_w_row(lip_w, pose_w, tid + 256, w2);
        load_w_row(lip_w, pose_w, tid + 384, w3);
#pragma unroll
        for (int k = 0; k < 26; ++k) {
            float q0 = 0.f, q1 = 0.f, q2 = 0.f, q3 = 0.f;
#pragma unroll
            for (int m = 0; m < 26; ++m) {
                if (m <= k) {
                    const float r = Rinv[m][k];
                    q0 = fmaf(w0[m], r, q0);
                    q1 = fmaf(w1[m], r, q1);
                    q2 = fmaf(w2[m], r, q2);
                    q3 = fmaf(w3[m], r, q3);
                }
            }
            float* qk = qt + k * 512 + tid;
            qk[0]   = q0;
            qk[128] = q1;
            qk[256] = q2;
            qk[384] = q3;
        }
    }
}

// ---------------------------------------------------------------------------
// out[B][512] = input[B][26] @ qt^T   (qt is [26][512])
// Block = 256 threads, 32 rows x 512 cols. x-tile staged in LDS with rows
// PADDED to 28 floats (112 B, 16B-aligned) so each row is read with 7
// ds_read_b128 instead of 26 ds_read_b32 (LDS-issue was the bottleneck).
// ---------------------------------------------------------------------------

__global__ __launch_bounds__(256) void out_gemm(const float* __restrict__ in,
                                                const float* __restrict__ qt,
                                                float* __restrict__ out) {
    __shared__ __align__(16) float xs[32 * 28];
    const int tid = threadIdx.x;
    const long base = (long)blockIdx.x * 32;

    // Stage 32x26 tile: 208 threads load f32x4, scatter 4 elements each into
    // the padded layout (div-by-26 compiles to magic-mul).
    if (tid < 208) {
        const float4 v = reinterpret_cast<const float4*>(in + base * 26)[tid];
        const float vals[4] = {v.x, v.y, v.z, v.w};
        const int e0 = tid * 4;
#pragma unroll
        for (int q = 0; q < 4; ++q) {
            const int e = e0 + q;
            const int r = e / 26;
            const int c = e - r * 26;
            xs[r * 28 + c] = vals[q];
        }
    }

    const int cg = tid & 127;             // column group: cols 4*cg .. 4*cg+3
    const int rh = tid >> 7;              // row half: 0 or 1

    f32x4 qf[26];
#pragma unroll
    for (int k = 0; k < 26; ++k)
        qf[k] = *reinterpret_cast<const f32x4*>(qt + k * 512 + cg * 4);
    __syncthreads();

    float* op = out + (base + (long)rh * 16) * 512 + cg * 4;
#pragma unroll
    for (int r = 0; r < 16; ++r) {
        const float* xr = xs + (rh * 16 + r) * 28;
        const f32x4 t0 = *reinterpret_cast<const f32x4*>(xr + 0);
        const f32x4 t1 = *reinterpret_cast<const f32x4*>(xr + 4);
        const f32x4 t2 = *reinterpret_cast<const f32x4*>(xr + 8);
        const f32x4 t3 = *reinterpret_cast<const f32x4*>(xr + 12);
        const f32x4 t4 = *reinterpret_cast<const f32x4*>(xr + 16);
        const f32x4 t5 = *reinterpret_cast<const f32x4*>(xr + 20);
        const f32x4 t6 = *reinterpret_cast<const f32x4*>(xr + 24);  // .z/.w unused
        float xv[26];
        xv[0]=t0.x;  xv[1]=t0.y;  xv[2]=t0.z;  xv[3]=t0.w;
        xv[4]=t1.x;  xv[5]=t1.y;  xv[6]=t1.z;  xv[7]=t1.w;
        xv[8]=t2.x;  xv[9]=t2.y;  xv[10]=t2.z; xv[11]=t2.w;
        xv[12]=t3.x; xv[13]=t3.y; xv[14]=t3.z; xv[15]=t3.w;
        xv[16]=t4.x; xv[17]=t4.y; xv[18]=t4.z; xv[19]=t4.w;
        xv[20]=t5.x; xv[21]=t5.y; xv[22]=t5.z; xv[23]=t5.w;
        xv[24]=t6.x; xv[25]=t6.y;
        f32x4 acc = {0.f, 0.f, 0.f, 0.f};
#pragma unroll
        for (int k = 0; k < 26; ++k) {
            acc.x = fmaf(xv[k], qf[k].x, acc.x);
            acc.y = fmaf(xv[k], qf[k].y, acc.y);
            acc.z = fmaf(xv[k], qf[k].z, acc.z);
            acc.w = fmaf(xv[k], qf[k].w, acc.w);
        }
        __builtin_nontemporal_store(acc,
            reinterpret_cast<f32x4*>(op + (long)r * 512));
    }
}

// ---------------------------------------------------------------------------

extern "C" void kernel_launch(void* const* d_in, const int* in_sizes, int n_in,
                              void* d_out, int out_size, void* d_ws, size_t ws_size,
                              hipStream_t stream) {
    const float* input  = (const float*)d_in[0];   // (B, 26)
    const float* pose_w = (const float*)d_in[1];   // (512, 6)
    const float* lip_w  = (const float*)d_in[2];   // (512, 20)
    float* out = (float*)d_out;                    // (B, 512)
    float* qt  = (float*)d_ws;                     // Q^T as [26][512] f32

    const int B = in_sizes[0] / 26;

    qr_kernel<<<1, 512, 0, stream>>>(pose_w, lip_w, qt);
    out_gemm<<<(B + 31) / 32, 256, 0, stream>>>(input, qt, out);
}